// Round 1
// baseline (878.757 us; speedup 1.0000x reference)
//
#include <hip/hip_runtime.h>

#define NFEAT 128

static inline size_t align_up(size_t x, size_t a) { return (x + a - 1) & ~(a - 1); }

// ---------------- degree histogram ----------------
__global__ __launch_bounds__(256) void k_hist(const int* __restrict__ src,
                                              const int* __restrict__ dst,
                                              int* __restrict__ cnt_out,
                                              int* __restrict__ cnt_in, int E) {
  for (int i = blockIdx.x * 256 + threadIdx.x; i < E; i += gridDim.x * 256) {
    atomicAdd(&cnt_out[src[i]], 1);
    atomicAdd(&cnt_in[dst[i]], 1);
  }
}

__global__ __launch_bounds__(256) void k_rsq(const int* __restrict__ cnt_out,
                                             const int* __restrict__ cnt_in,
                                             float* __restrict__ rsq_out,
                                             float* __restrict__ rsq_in, int N) {
  int i = blockIdx.x * 256 + threadIdx.x;
  if (i < N) {
    int co = cnt_out[i]; if (co < 1) co = 1;
    int ci = cnt_in[i];  if (ci < 1) ci = 1;
    rsq_out[i] = 1.0f / sqrtf((float)co);
    rsq_in[i]  = 1.0f / sqrtf((float)ci);
  }
}

// ---------------- exclusive scan (3 phases) ----------------
__global__ __launch_bounds__(256) void k_scan1(const int* __restrict__ in,
                                               int* __restrict__ out,
                                               int* __restrict__ bsum, int n) {
  __shared__ int tmp[256];
  int t = threadIdx.x;
  int i = blockIdx.x * 256 + t;
  int v = (i < n) ? in[i] : 0;
  tmp[t] = v;
  __syncthreads();
  for (int off = 1; off < 256; off <<= 1) {
    int y = (t >= off) ? tmp[t - off] : 0;
    __syncthreads();
    tmp[t] += y;
    __syncthreads();
  }
  int incl = tmp[t];
  if (i < n) out[i] = incl - v;   // exclusive
  if (t == 255) bsum[blockIdx.x] = incl;
}

__global__ __launch_bounds__(512) void k_scan2(int* __restrict__ bsum,
                                               int* __restrict__ bscan, int nb) {
  __shared__ int tmp[512];
  int t = threadIdx.x;
  int v = (t < nb) ? bsum[t] : 0;
  tmp[t] = v;
  __syncthreads();
  for (int off = 1; off < 512; off <<= 1) {
    int y = (t >= off) ? tmp[t - off] : 0;
    __syncthreads();
    tmp[t] += y;
    __syncthreads();
  }
  bscan[t] = tmp[t] - v;          // exclusive
}

__global__ __launch_bounds__(256) void k_scan3(int* __restrict__ out,
                                               const int* __restrict__ bscan,
                                               int* __restrict__ cursor, int n, int E) {
  int i = blockIdx.x * 256 + threadIdx.x;
  if (i < n) {
    int r = out[i] + bscan[blockIdx.x];
    out[i] = r;
    cursor[i] = r;
  }
  if (i == 0) out[n] = E;
}

// ---------------- scatter edges into dst-CSR ----------------
__global__ __launch_bounds__(256) void k_scatter(const int* __restrict__ src,
                                                 const int* __restrict__ dst,
                                                 int* __restrict__ cursor,
                                                 int* __restrict__ col, int E) {
  for (int i = blockIdx.x * 256 + threadIdx.x; i < E; i += gridDim.x * 256) {
    int d = dst[i];
    int p = atomicAdd(&cursor[d], 1);
    col[p] = src[i];
  }
}

// ---------------- fused pre-transform + SGEMM ----------------
// Y[r][c] = rsq_out[r] * sum_k f(X[r][k]) * W[k][c]
// mode 0: f = identity   mode 1: f = relu(x*bnscale[k]+bnshift[k])
#define GB_ROWS 64
#define GB_COLS 64
#define GK 16
#define XLD 68

__global__ __launch_bounds__(256) void k_gemm(
    const float* __restrict__ X, const float* __restrict__ W,
    float* __restrict__ Y, const float* __restrict__ rsq_out,
    const float* __restrict__ bnscale, const float* __restrict__ bnshift,
    int Nrows, int Ccols, int mode) {
  __shared__ __align__(16) float Xs[GK][XLD];  // transposed: Xs[k][r]
  __shared__ __align__(16) float Ws[GK][XLD];  // Ws[k][c]
  const int tid = threadIdx.x;
  const int tx = tid & 15;   // col group
  const int ty = tid >> 4;   // row group
  const int rowBase = blockIdx.x * GB_ROWS;
  const int colBase = blockIdx.y * GB_COLS;
  float acc[4][4] = {};

  for (int k0 = 0; k0 < NFEAT; k0 += GK) {
    // stage X: 64 rows x 16 k
#pragma unroll
    for (int i = 0; i < 4; ++i) {
      int e = tid + i * 256;
      int r = e >> 4, k = e & 15;
      int gr = rowBase + r;
      float v = 0.0f;
      if (gr < Nrows) v = X[(size_t)gr * NFEAT + k0 + k];
      if (mode) {
        v = v * bnscale[k0 + k] + bnshift[k0 + k];
        v = v > 0.0f ? v : 0.0f;
      }
      Xs[k][r] = v;
    }
    // stage W: 16 k x 64 cols
#pragma unroll
    for (int i = 0; i < 4; ++i) {
      int e = tid + i * 256;
      int k = e >> 6, c = e & 63;
      Ws[k][c] = W[(size_t)(k0 + k) * Ccols + colBase + c];
    }
    __syncthreads();
#pragma unroll
    for (int k = 0; k < GK; ++k) {
      const float4 xv = *(const float4*)&Xs[k][ty * 4];
      const float4 wv = *(const float4*)&Ws[k][tx * 4];
      acc[0][0] += xv.x * wv.x; acc[0][1] += xv.x * wv.y; acc[0][2] += xv.x * wv.z; acc[0][3] += xv.x * wv.w;
      acc[1][0] += xv.y * wv.x; acc[1][1] += xv.y * wv.y; acc[1][2] += xv.y * wv.z; acc[1][3] += xv.y * wv.w;
      acc[2][0] += xv.z * wv.x; acc[2][1] += xv.z * wv.y; acc[2][2] += xv.z * wv.z; acc[2][3] += xv.z * wv.w;
      acc[3][0] += xv.w * wv.x; acc[3][1] += xv.w * wv.y; acc[3][2] += xv.w * wv.z; acc[3][3] += xv.w * wv.w;
    }
    __syncthreads();
  }
#pragma unroll
  for (int i = 0; i < 4; ++i) {
    int gr = rowBase + ty * 4 + i;
    if (gr < Nrows) {
      float s = rsq_out[gr];
      float4 o = make_float4(acc[i][0] * s, acc[i][1] * s, acc[i][2] * s, acc[i][3] * s);
      *(float4*)&Y[(size_t)gr * Ccols + colBase + tx * 4] = o;
    }
  }
}

// ---------------- CSR SpMM: out[n] = rsq_in[n] * sum_{e in row n} xW[col[e]] + bias ----------------
template <int F>
__global__ __launch_bounds__(256) void k_spmm(const int* __restrict__ row_ptr,
                                              const int* __restrict__ colidx,
                                              const float* __restrict__ xW,
                                              float* __restrict__ out,
                                              const float* __restrict__ rsq_in,
                                              const float* __restrict__ bias, int Nrows) {
  constexpr int L = F / 4;                  // lanes per node
  const int node = blockIdx.x * (256 / L) + threadIdx.x / L;
  const int lane = threadIdx.x % L;
  if (node >= Nrows) return;
  const int e0 = row_ptr[node];
  const int e1 = row_ptr[node + 1];
  float4 acc = make_float4(0.f, 0.f, 0.f, 0.f);
  int e = e0;
  for (; e + 1 < e1; e += 2) {
    int s0 = colidx[e];
    int s1 = colidx[e + 1];
    float4 v0 = *(const float4*)&xW[(size_t)s0 * F + lane * 4];
    float4 v1 = *(const float4*)&xW[(size_t)s1 * F + lane * 4];
    acc.x += v0.x; acc.y += v0.y; acc.z += v0.z; acc.w += v0.w;
    acc.x += v1.x; acc.y += v1.y; acc.z += v1.z; acc.w += v1.w;
  }
  if (e < e1) {
    int s0 = colidx[e];
    float4 v0 = *(const float4*)&xW[(size_t)s0 * F + lane * 4];
    acc.x += v0.x; acc.y += v0.y; acc.z += v0.z; acc.w += v0.w;
  }
  const float sc = rsq_in[node];
  const float4 b = *(const float4*)&bias[lane * 4];
  float4 o = make_float4(acc.x * sc + b.x, acc.y * sc + b.y, acc.z * sc + b.z, acc.w * sc + b.w);
  *(float4*)&out[(size_t)node * F + lane * 4] = o;
}

// ---------------- BatchNorm stats + finalize ----------------
__global__ __launch_bounds__(256) void k_bn_stats(const float* __restrict__ h,
                                                  float* __restrict__ sum,
                                                  float* __restrict__ sumsq, int Nrows) {
  const int f = threadIdx.x & 127;
  const int half = threadIdx.x >> 7;
  float s = 0.f, ss = 0.f;
  for (int r = blockIdx.x * 2 + half; r < Nrows; r += gridDim.x * 2) {
    float v = h[(size_t)r * NFEAT + f];
    s += v;
    ss += v * v;
  }
  __shared__ float ls[256], lss[256];
  ls[threadIdx.x] = s;
  lss[threadIdx.x] = ss;
  __syncthreads();
  if (half == 0) {
    atomicAdd(&sum[f], ls[f] + ls[f + 128]);
    atomicAdd(&sumsq[f], lss[f] + lss[f + 128]);
  }
}

__global__ __launch_bounds__(128) void k_bn_final(const float* __restrict__ sum,
                                                  const float* __restrict__ sumsq,
                                                  const float* __restrict__ gamma,
                                                  const float* __restrict__ beta,
                                                  float* __restrict__ scale,
                                                  float* __restrict__ shift, int Nrows) {
  int f = threadIdx.x;
  float inv_n = 1.0f / (float)Nrows;
  float mean = sum[f] * inv_n;
  float var = sumsq[f] * inv_n - mean * mean;
  if (var < 0.f) var = 0.f;
  float sc = gamma[f] * (1.0f / sqrtf(var + 1e-5f));
  scale[f] = sc;
  shift[f] = beta[f] - mean * sc;
}

extern "C" void kernel_launch(void* const* d_in, const int* in_sizes, int n_in,
                              void* d_out, int out_size, void* d_ws, size_t ws_size,
                              hipStream_t stream) {
  const float* in_feat = (const float*)d_in[0];
  const int* src = (const int*)d_in[1];
  const int* dst = (const int*)d_in[2];
  const float* W0 = (const float*)d_in[3];
  const float* b0 = (const float*)d_in[4];
  const float* W1 = (const float*)d_in[5];
  const float* b1 = (const float*)d_in[6];
  const float* W2 = (const float*)d_in[7];
  const float* b2 = (const float*)d_in[8];
  const float* gamma0 = (const float*)d_in[9];
  const float* beta0 = (const float*)d_in[10];
  const float* gamma1 = (const float*)d_in[11];
  const float* beta1 = (const float*)d_in[12];
  float* out = (float*)d_out;

  const int N = in_sizes[0] / NFEAT;
  const int E = in_sizes[1];
  const int C2 = in_sizes[7] / NFEAT;  // 64

  // ---- carve workspace ----
  char* p = (char*)d_ws;
  auto carve = [&](size_t bytes) {
    char* q = p;
    p += align_up(bytes, 256);
    return q;
  };
  int* cnt_out = (int*)carve((size_t)N * 4);
  int* cnt_in = (int*)carve((size_t)N * 4);
  int* row_ptr = (int*)carve((size_t)(N + 1) * 4);
  int* cursor = (int*)carve((size_t)N * 4);
  int* bsum = (int*)carve(512 * 4);
  int* bscan = (int*)carve(512 * 4);
  int* col = (int*)carve((size_t)E * 4);
  float* rsq_out = (float*)carve((size_t)N * 4);
  float* rsq_in = (float*)carve((size_t)N * 4);
  float* bn_sum0 = (float*)carve(128 * 4);
  float* bn_sumsq0 = (float*)carve(128 * 4);
  float* bn_sum1 = (float*)carve(128 * 4);
  float* bn_sumsq1 = (float*)carve(128 * 4);
  float* bn_scale0 = (float*)carve(128 * 4);
  float* bn_shift0 = (float*)carve(128 * 4);
  float* bn_scale1 = (float*)carve(128 * 4);
  float* bn_shift1 = (float*)carve(128 * 4);
  float* bufA = (float*)carve((size_t)N * NFEAT * 4);
  float* bufB = (float*)carve((size_t)N * NFEAT * 4);

  // ---- zero-init (ws is poisoned 0xAA every launch) ----
  hipMemsetAsync(cnt_out, 0, (size_t)N * 4, stream);
  hipMemsetAsync(cnt_in, 0, (size_t)N * 4, stream);
  hipMemsetAsync(bn_sum0, 0, 4 * 128 * 4, stream);  // bn_sum0..bn_sumsq1 contiguous

  const int NB = (N + 255) / 256;

  // ---- degrees + CSR build ----
  k_hist<<<2048, 256, 0, stream>>>(src, dst, cnt_out, cnt_in, E);
  k_rsq<<<NB, 256, 0, stream>>>(cnt_out, cnt_in, rsq_out, rsq_in, N);
  k_scan1<<<NB, 256, 0, stream>>>(cnt_in, row_ptr, bsum, N);
  k_scan2<<<1, 512, 0, stream>>>(bsum, bscan, NB);
  k_scan3<<<NB, 256, 0, stream>>>(row_ptr, bscan, cursor, N, E);
  k_scatter<<<2048, 256, 0, stream>>>(src, dst, cursor, col, E);

  const int GR = (N + GB_ROWS - 1) / GB_ROWS;

  // ---- layer 0 ----
  k_gemm<<<dim3(GR, NFEAT / GB_COLS), 256, 0, stream>>>(in_feat, W0, bufA, rsq_out,
                                                        nullptr, nullptr, N, NFEAT, 0);
  k_spmm<NFEAT><<<(N + 7) / 8, 256, 0, stream>>>(row_ptr, col, bufA, bufB, rsq_in, b0, N);
  k_bn_stats<<<512, 256, 0, stream>>>(bufB, bn_sum0, bn_sumsq0, N);
  k_bn_final<<<1, 128, 0, stream>>>(bn_sum0, bn_sumsq0, gamma0, beta0, bn_scale0, bn_shift0, N);

  // ---- layer 1 ----
  k_gemm<<<dim3(GR, NFEAT / GB_COLS), 256, 0, stream>>>(bufB, W1, bufA, rsq_out,
                                                        bn_scale0, bn_shift0, N, NFEAT, 1);
  k_spmm<NFEAT><<<(N + 7) / 8, 256, 0, stream>>>(row_ptr, col, bufA, bufB, rsq_in, b1, N);
  k_bn_stats<<<512, 256, 0, stream>>>(bufB, bn_sum1, bn_sumsq1, N);
  k_bn_final<<<1, 128, 0, stream>>>(bn_sum1, bn_sumsq1, gamma1, beta1, bn_scale1, bn_shift1, N);

  // ---- layer 2 (output 64 classes) ----
  k_gemm<<<dim3(GR, 1), 256, 0, stream>>>(bufB, W2, bufA, rsq_out,
                                          bn_scale1, bn_shift1, N, C2, 1);
  k_spmm<64><<<(N + 15) / 16, 256, 0, stream>>>(row_ptr, col, bufA, out, rsq_in, b2, N);
}